// Round 8
// baseline (374.549 us; speedup 1.0000x reference)
//
#include <hip/hip_runtime.h>

#define S_LEN 2048
#define NH    16
#define NB    4
#define NT    32                 // S_LEN / 64 tiles
#define CLO  -4.605170186f       // log(1e-2)
#define CHI   4.605170186f       // log(1e2)
#define LOG2E 1.44269504f

#if __has_builtin(__builtin_amdgcn_exp2f)
#define EXP2F(x) __builtin_amdgcn_exp2f(x)
#else
#define EXP2F(x) exp2f(x)
#endif

using bf16x8 = __attribute__((ext_vector_type(8))) short;
using f32x4  = __attribute__((ext_vector_type(4))) float;
typedef unsigned int   u32;
typedef unsigned short u16;

__device__ __forceinline__ u16 f2bf(float f){           // RNE f32->bf16
    u32 x = __float_as_uint(f);
    x += 0x7fffu + ((x >> 16) & 1u);
    return (u16)(x >> 16);
}
__device__ __forceinline__ u32 pk2(float a, float b){
    return (u32)f2bf(a) | ((u32)f2bf(b) << 16);
}
// swizzled byte offset into a [rows][64] bf16 tile (128B rows).
// XOR of byte bits 4-6 with row&7 spreads 16B column slots across banks (G4).
// prep applies swz on write, so the SAME math reads the tiles from global
// (once-read operands) or from LDS (stage_lds copies bytes linearly).
__device__ __forceinline__ int swz(int row, int bcol){
    return row*128 + (bcol ^ ((row & 7) << 4));
}
__device__ __forceinline__ bf16x8 ldfrag(const u16* base, int row, int bcol){
    return *(const bf16x8*)((const char*)base + swz(row, bcol));
}
#define MFMA16(a, b, c) __builtin_amdgcn_mfma_f32_16x16x32_bf16(a, b, c, 0, 0, 0)

// ---------------- fast path: prep + hybrid staging ----------------
// K/V tiles (read by all 4 waves of a block): LDS-staged via global_load_lds,
// double-buffered -> 4x dedup of the dominant traffic.
// Q (k1) / K-strips (k2) (read ONCE per block): direct from global -> no
// staging overhead (m169 lesson, applied only where there is no sharing).
// Softmax algebra: prep scales Qhat by scale*log2e; QK^T accumulators are
// initialized to -scale*log2e (free C-operand), so p = 2^s via raw v_exp —
// no per-element mul/sub. p = exp(sim - scale) exactly; |sim| <= scale
// statically (unit vectors) so this is exact softmax weighting (no max pass).

// Stage one 8KB (64x64 bf16, pre-swizzled in global) tile into LDS linearly.
// Wave w copies bytes [w*2048, w*2048+2048) via 2x global_load_lds_dwordx4.
// LDS dest is wave-uniform base + lane*16 (HW rule); global src is per-lane.
__device__ __forceinline__ void stage_lds(const u16* __restrict__ gsrc,
                                          u16* lds, int w, int lane){
    #pragma unroll
    for (int c = 0; c < 2; ++c){
        __builtin_amdgcn_global_load_lds(
            (const __attribute__((address_space(1))) void*)(const void*)
                (gsrc + w*1024 + c*512 + lane*8),
            (__attribute__((address_space(3))) void*)(void*)
                (lds + w*1024 + c*512),
            16, 0, 0);
    }
}

// Prep: normalize Q (x scale*log2e) and K to bf16; transpose V, V_kq to
// [d][j] bf16. Output layout: tensor[bh][tile][row][col] with swz() applied
// inside each 8KB tile. grid: (2048 = 64bh x 32tile, 4 tensors), block 256.
__global__ __launch_bounds__(256, 4)
void prep_kern(const float* __restrict__ q, const float* __restrict__ k,
               const float* __restrict__ v, const float* __restrict__ vkq,
               const float* __restrict__ ssc,
               u16* __restrict__ qn, u16* __restrict__ kn,
               u16* __restrict__ vt, u16* __restrict__ vkt){
    const int tensor = blockIdx.y;
    const int bh = blockIdx.x >> 5;
    const int t  = blockIdx.x & 31;
    const int b  = bh >> 4;
    const int h  = bh & 15;
    const int row = threadIdx.x >> 2;
    const int qq  = threadIdx.x & 3;

    const float* srcs[4] = {q, k, v, vkq};
    u16*         dsts[4] = {qn, kn, vt, vkt};
    const float* src = srcs[tensor] + ((size_t)b*S_LEN + t*64)*1024 + (size_t)h*64;
    u16*         dst = dsts[tensor] + ((size_t)bh*32 + t)*4096;

    const float4* p = (const float4*)(src + row*1024 + qq*16);
    float4 a = p[0], bb = p[1], c = p[2], d = p[3];

    __shared__ float T[64][65];

    if (tensor < 2){
        float ss = a.x*a.x + a.y*a.y + a.z*a.z + a.w*a.w
                 + bb.x*bb.x + bb.y*bb.y + bb.z*bb.z + bb.w*bb.w
                 + c.x*c.x + c.y*c.y + c.z*c.z + c.w*c.w
                 + d.x*d.x + d.y*d.y + d.z*d.z + d.w*d.w;
        ss += __shfl_xor(ss, 1);
        ss += __shfl_xor(ss, 2);
        const float mul = (tensor == 0)
            ? __expf(fminf(fmaxf(ssc[h], CLO), CHI)) * LOG2E : 1.0f;
        const float sc  = mul / fmaxf(sqrtf(ss), 1e-12f);
        uint4 c0, c1;
        c0.x = pk2(a.x*sc, a.y*sc);  c0.y = pk2(a.z*sc, a.w*sc);
        c0.z = pk2(bb.x*sc, bb.y*sc);c0.w = pk2(bb.z*sc, bb.w*sc);
        c1.x = pk2(c.x*sc, c.y*sc);  c1.y = pk2(c.z*sc, c.w*sc);
        c1.z = pk2(d.x*sc, d.y*sc);  c1.w = pk2(d.z*sc, d.w*sc);
        *(uint4*)((char*)dst + swz(row, qq*32     )) = c0;
        *(uint4*)((char*)dst + swz(row, qq*32 + 16)) = c1;
    } else {
        float* tr = &T[row][qq*16];
        tr[0]=a.x; tr[1]=a.y; tr[2]=a.z; tr[3]=a.w;
        tr[4]=bb.x;tr[5]=bb.y;tr[6]=bb.z;tr[7]=bb.w;
        tr[8]=c.x; tr[9]=c.y; tr[10]=c.z;tr[11]=c.w;
        tr[12]=d.x;tr[13]=d.y;tr[14]=d.z;tr[15]=d.w;
        __syncthreads();
        float f[16];
        #pragma unroll
        for (int jj = 0; jj < 16; ++jj) f[jj] = T[qq*16 + jj][row];   // [d=row][j]
        uint4 c0, c1;
        c0.x = pk2(f[0], f[1]);   c0.y = pk2(f[2], f[3]);
        c0.z = pk2(f[4], f[5]);   c0.w = pk2(f[6], f[7]);
        c1.x = pk2(f[8], f[9]);   c1.y = pk2(f[10],f[11]);
        c1.z = pk2(f[12],f[13]);  c1.w = pk2(f[14],f[15]);
        *(uint4*)((char*)dst + swz(row, qq*32     )) = c0;
        *(uint4*)((char*)dst + swz(row, qq*32 + 16)) = c1;
    }
}

// Kernel 1 (fast): flash over j, 2-phase pipelined (double-buffered K/V via
// global_load_lds, next tile's DMA issued BEFORE this tile's compute, ONE
// __syncthreads per tile). Q read once -> direct from global. 48KB LDS ->
// 3 blocks/CU (12 waves): extra waves hide the per-tile vmcnt drain.
// Two 16-row strips per wave (128-row i-block) for K/V reuse. Denominator
// reduction deferred to the epilogue (lane-local partials in the loop).
__global__ __launch_bounds__(256, 3)
void k1f(const u16* __restrict__ qn, const u16* __restrict__ kn,
         const u16* __restrict__ vt, const float* __restrict__ ssc,
         float* __restrict__ out, float* __restrict__ il_s){
    const int bid = (blockIdx.x & 7) * 128 + (blockIdx.x >> 3);  // XCD swizzle
    const int bh  = bid >> 4;          // 16 i-blocks of 128 rows per (b,h)
    const int ib  = bid & 15;
    const int b   = bh >> 4;
    const int h   = bh & 15;
    const int lane = threadIdx.x & 63;
    const int w    = threadIdx.x >> 6;
    const int g    = lane >> 4;
    const int li   = lane & 15;

    const float c2 = __expf(fminf(fmaxf(ssc[h], CLO), CHI)) * LOG2E;
    const f32x4 minit = {-c2, -c2, -c2, -c2};

    __shared__ __align__(16) u16 Kb[2][4096];
    __shared__ __align__(16) u16 Vb[2][4096];
    __shared__ __align__(16) u16 Pl[4][2][1024];   // per-wave, per-strip

    const size_t tb = (size_t)bh*32;
    stage_lds(kn + tb*4096, Kb[0], w, lane);
    stage_lds(vt + tb*4096, Vb[0], w, lane);

    // Q fragments: read once per block -> direct from pre-swizzled global
    bf16x8 qf[2][2];
    #pragma unroll
    for (int st = 0; st < 2; ++st){
        const u16* gq = qn + (tb + 2*ib + st)*4096;
        qf[st][0] = ldfrag(gq, w*16 + li, g*16);
        qf[st][1] = ldfrag(gq, w*16 + li, g*16 + 64);
    }
    __syncthreads();                                  // prologue drain

    const f32x4 zero = {0.f, 0.f, 0.f, 0.f};
    f32x4 acc_o[2][4];
    float lrow[2][4];                                 // lane-local partials
    #pragma unroll
    for (int st = 0; st < 2; ++st)
        #pragma unroll
        for (int i = 0; i < 4; ++i){ acc_o[st][i] = zero; lrow[st][i] = 0.f; }

    for (int jt = 0; jt < NT; ++jt){
        const int cur = jt & 1;
        // issue next tile's DMA early; latency hides under this tile's compute
        if (jt + 1 < NT){
            stage_lds(kn + (tb + jt + 1)*4096, Kb[cur^1], w, lane);
            stage_lds(vt + (tb + jt + 1)*4096, Vb[cur^1], w, lane);
        }

        f32x4 s[2][4];
        #pragma unroll
        for (int st = 0; st < 2; ++st)
            #pragma unroll
            for (int n = 0; n < 4; ++n) s[st][n] = minit;   // C-in = -scale*log2e

        __builtin_amdgcn_s_setprio(1);
        #pragma unroll
        for (int n = 0; n < 4; ++n){
            const bf16x8 kf0 = ldfrag(Kb[cur], n*16 + li, g*16);
            const bf16x8 kf1 = ldfrag(Kb[cur], n*16 + li, g*16 + 64);
            #pragma unroll
            for (int st = 0; st < 2; ++st){
                s[st][n] = MFMA16(qf[st][0], kf0, s[st][n]);
                s[st][n] = MFMA16(qf[st][1], kf1, s[st][n]);
            }
        }
        __builtin_amdgcn_s_setprio(0);

        // p = 2^s (s already = (sim - scale)*log2e); lane-local partial sums.
        // D-layout: row i = g*4+r, col j = n*16+li
        #pragma unroll
        for (int st = 0; st < 2; ++st){
            float p[4][4];
            #pragma unroll
            for (int n = 0; n < 4; ++n)
                #pragma unroll
                for (int r = 0; r < 4; ++r){
                    p[n][r] = EXP2F(s[st][n][r]);
                    lrow[st][r] += p[n][r];
                }
            u16* pw = &Pl[w][st][0];
            #pragma unroll
            for (int n = 0; n < 4; ++n)
                #pragma unroll
                for (int r = 0; r < 4; ++r)
                    *(u16*)((char*)pw + swz(g*4 + r, n*32 + li*2)) = f2bf(p[n][r]);
        }

        // PV: each V fragment feeds both strips; P is wave-private (compiler
        // inserts the wave-local lgkm wait for the write->read dependency).
        __builtin_amdgcn_s_setprio(1);
        #pragma unroll
        for (int ks = 0; ks < 2; ++ks){
            const bf16x8 pf0 = ldfrag(&Pl[w][0][0], li, g*16 + ks*64);
            const bf16x8 pf1 = ldfrag(&Pl[w][1][0], li, g*16 + ks*64);
            #pragma unroll
            for (int dt = 0; dt < 4; ++dt){
                const bf16x8 vf = ldfrag(Vb[cur], dt*16 + li, g*16 + ks*64);
                acc_o[0][dt] = MFMA16(pf0, vf, acc_o[0][dt]);
                acc_o[1][dt] = MFMA16(pf1, vf, acc_o[1][dt]);
            }
        }
        __builtin_amdgcn_s_setprio(0);

        __syncthreads();   // vm+lgkm drain + barrier: tile jt+1 resident,
                           // tile jt's reads finished -> buffers reusable
    }

    #pragma unroll
    for (int st = 0; st < 2; ++st)
        #pragma unroll
        for (int r = 0; r < 4; ++r){
            float v0 = lrow[st][r];              // deferred cross-lane reduce
            v0 += __shfl_xor(v0, 1);
            v0 += __shfl_xor(v0, 2);
            v0 += __shfl_xor(v0, 4);
            v0 += __shfl_xor(v0, 8);
            const float il = 1.0f / v0;
            const int   i  = ib*128 + st*64 + w*16 + g*4 + r;
            const size_t ob = (((size_t)b*S_LEN + i)*NH + h)*64;
            #pragma unroll
            for (int dt = 0; dt < 4; ++dt)
                out[ob + dt*16 + li] = acc_o[st][dt][r] * il;
            if (li == 0)
                il_s[bh*S_LEN + i] = il;
        }
}

// Kernel 2 (fast): attn^T . v_kq, same hybrid structure (128 j-rows/block):
// Q/V_kq tiles LDS-staged (shared by 4 waves), this block's K-strips read
// once -> direct from global. sim recomputed with swapped operands so P^T
// lands in j-row strips; p = 2^s * il_i.
__global__ __launch_bounds__(256, 3)
void k2f(const u16* __restrict__ qn, const u16* __restrict__ kn,
         const u16* __restrict__ vkt, const float* __restrict__ ssc,
         float* __restrict__ out2, const float* __restrict__ il_s){
    const int bid = (blockIdx.x & 7) * 128 + (blockIdx.x >> 3);
    const int bh  = bid >> 4;
    const int jb  = bid & 15;
    const int b   = bh >> 4;
    const int h   = bh & 15;
    const int lane = threadIdx.x & 63;
    const int w    = threadIdx.x >> 6;
    const int g    = lane >> 4;
    const int li   = lane & 15;

    const float c2 = __expf(fminf(fmaxf(ssc[h], CLO), CHI)) * LOG2E;
    const f32x4 minit = {-c2, -c2, -c2, -c2};

    __shared__ __align__(16) u16 Qb[2][4096];
    __shared__ __align__(16) u16 Vb[2][4096];
    __shared__ __align__(16) u16 Pl[4][2][1024];

    const size_t tb = (size_t)bh*32;
    stage_lds(qn + tb*4096, Qb[0], w, lane);
    stage_lds(vkt + tb*4096, Vb[0], w, lane);

    // K-strip fragments: read once per block -> direct from global
    bf16x8 kf[2][2];                       // A-frags: rows = j strips
    #pragma unroll
    for (int st = 0; st < 2; ++st){
        const u16* gk = kn + (tb + 2*jb + st)*4096;
        kf[st][0] = ldfrag(gk, w*16 + li, g*16);
        kf[st][1] = ldfrag(gk, w*16 + li, g*16 + 64);
    }
    __syncthreads();

    const f32x4 zero = {0.f, 0.f, 0.f, 0.f};
    f32x4 acc[2][4];
    #pragma unroll
    for (int st = 0; st < 2; ++st)
        #pragma unroll
        for (int i = 0; i < 4; ++i) acc[st][i] = zero;

    for (int it = 0; it < NT; ++it){
        const int cur = it & 1;
        if (it + 1 < NT){
            stage_lds(qn  + (tb + it + 1)*4096, Qb[cur^1], w, lane);
            stage_lds(vkt + (tb + it + 1)*4096, Vb[cur^1], w, lane);
        }
        // issue stat loads early; latency hides under QK^T (shared by strips)
        float ii[4];
        #pragma unroll
        for (int n = 0; n < 4; ++n)
            ii[n] = il_s[bh*S_LEN + it*64 + n*16 + li];

        f32x4 s[2][4];                     // row j = g*4+r, col i = n*16+li
        #pragma unroll
        for (int st = 0; st < 2; ++st)
            #pragma unroll
            for (int n = 0; n < 4; ++n) s[st][n] = minit;

        __builtin_amdgcn_s_setprio(1);
        #pragma unroll
        for (int n = 0; n < 4; ++n){
            const bf16x8 qb0 = ldfrag(Qb[cur], n*16 + li, g*16);
            const bf16x8 qb1 = ldfrag(Qb[cur], n*16 + li, g*16 + 64);
            #pragma unroll
            for (int st = 0; st < 2; ++st){
                s[st][n] = MFMA16(kf[st][0], qb0, s[st][n]);
                s[st][n] = MFMA16(kf[st][1], qb1, s[st][n]);
            }
        }
        __builtin_amdgcn_s_setprio(0);

        #pragma unroll
        for (int st = 0; st < 2; ++st){
            u16* pw = &Pl[w][st][0];
            #pragma unroll
            for (int n = 0; n < 4; ++n)
                #pragma unroll
                for (int r = 0; r < 4; ++r){
                    const float pv = EXP2F(s[st][n][r]) * ii[n];
                    *(u16*)((char*)pw + swz(g*4 + r, n*32 + li*2)) = f2bf(pv);
                }
        }

        __builtin_amdgcn_s_setprio(1);
        #pragma unroll
        for (int ks = 0; ks < 2; ++ks){
            const bf16x8 pf0 = ldfrag(&Pl[w][0][0], li, g*16 + ks*64);
            const bf16x8 pf1 = ldfrag(&Pl[w][1][0], li, g*16 + ks*64);
            #pragma unroll
            for (int dt = 0; dt < 4; ++dt){
                const bf16x8 vf = ldfrag(Vb[cur], dt*16 + li, g*16 + ks*64);
                acc[0][dt] = MFMA16(pf0, vf, acc[0][dt]);
                acc[1][dt] = MFMA16(pf1, vf, acc[1][dt]);
            }
        }
        __builtin_amdgcn_s_setprio(0);

        __syncthreads();
    }

    #pragma unroll
    for (int st = 0; st < 2; ++st)
        #pragma unroll
        for (int r = 0; r < 4; ++r){
            const int j = jb*128 + st*64 + w*16 + g*4 + r;
            const size_t ob = (((size_t)b*S_LEN + j)*NH + h)*64;
            #pragma unroll
            for (int dt = 0; dt < 4; ++dt)
                out2[ob + dt*16 + li] = acc[st][dt][r];
        }
}

// ---------------- fallback path (small ws): round-0 fused staging ----------

__device__ __forceinline__ void stage_rows(const float* __restrict__ src,
                                           u16* dst, float mul){
    const int t   = threadIdx.x;
    const int row = t >> 2;
    const int qq  = t & 3;
    const float4* p = (const float4*)(src + row*1024 + qq*16);
    float4 a = p[0], b = p[1], c = p[2], d = p[3];
    float ss = a.x*a.x + a.y*a.y + a.z*a.z + a.w*a.w
             + b.x*b.x + b.y*b.y + b.z*b.z + b.w*b.w
             + c.x*c.x + c.y*c.y + c.z*c.z + c.w*c.w
             + d.x*d.x + d.y*d.y + d.z*d.z + d.w*d.w;
    ss += __shfl_xor(ss, 1);
    ss += __shfl_xor(ss, 2);
    const float sc = mul / fmaxf(sqrtf(ss), 1e-12f);
    uint4 c0, c1;
    c0.x = pk2(a.x*sc, a.y*sc); c0.y = pk2(a.z*sc, a.w*sc);
    c0.z = pk2(b.x*sc, b.y*sc); c0.w = pk2(b.z*sc, b.w*sc);
    c1.x = pk2(c.x*sc, c.y*sc); c1.y = pk2(c.z*sc, c.w*sc);
    c1.z = pk2(d.x*sc, d.y*sc); c1.w = pk2(d.z*sc, d.w*sc);
    *(uint4*)((char*)dst + swz(row, qq*32     )) = c0;
    *(uint4*)((char*)dst + swz(row, qq*32 + 16)) = c1;
}

__device__ __forceinline__ void stage_T(const float* __restrict__ src, u16* dst){
    const int t  = threadIdx.x;
    const int dd = t & 63;
    const int jb = (t >> 6) << 4;
    float f[16];
    #pragma unroll
    for (int r = 0; r < 16; ++r) f[r] = src[(size_t)(jb + r)*1024 + dd];
    uint4 c0, c1;
    c0.x = pk2(f[0], f[1]);   c0.y = pk2(f[2], f[3]);
    c0.z = pk2(f[4], f[5]);   c0.w = pk2(f[6], f[7]);
    c1.x = pk2(f[8], f[9]);   c1.y = pk2(f[10],f[11]);
    c1.z = pk2(f[12],f[13]);  c1.w = pk2(f[14],f[15]);
    *(uint4*)((char*)dst + swz(dd, jb*2     )) = c0;
    *(uint4*)((char*)dst + swz(dd, jb*2 + 16)) = c1;
}

__global__ __launch_bounds__(256, 2)
void k1_flash(const float* __restrict__ q, const float* __restrict__ k,
              const float* __restrict__ v, const float* __restrict__ ssc,
              float* __restrict__ out, float* __restrict__ m_s,
              float* __restrict__ il_s){
    const int blk = blockIdx.x;
    const int bh  = blk >> 5;
    const int ib  = blk & 31;
    const int b   = bh >> 4;
    const int h   = bh & 15;
    const int lane = threadIdx.x & 63;
    const int w    = threadIdx.x >> 6;
    const int g    = lane >> 4;
    const int li   = lane & 15;

    const size_t base  = ((size_t)b*S_LEN)*1024 + (size_t)h*64;
    const float  scale = __expf(fminf(fmaxf(ssc[h], CLO), CHI));

    __shared__ __align__(16) u16 Ql[4096];
    __shared__ __align__(16) u16 Kl[4096];
    __shared__ __align__(16) u16 Vl[4096];
    __shared__ __align__(16) u16 Pl[4][1024];

    stage_rows(q + base + (size_t)ib*64*1024, Ql, scale);
    __syncthreads();
    const bf16x8 qf0 = ldfrag(Ql, w*16 + li, g*16);
    const bf16x8 qf1 = ldfrag(Ql, w*16 + li, g*16 + 64);

    const f32x4 zero = {0.f, 0.f, 0.f, 0.f};
    f32x4 acc_o[4];
    float mrow[4], lrow[4];
    #pragma unroll
    for (int i = 0; i < 4; ++i){ acc_o[i] = zero; mrow[i] = -1e30f; lrow[i] = 0.f; }

    for (int jt = 0; jt < NT; ++jt){
        __syncthreads();
        stage_rows(k + base + (size_t)jt*64*1024, Kl, 1.0f);
        stage_T  (v + base + (size_t)jt*64*1024, Vl);
        __syncthreads();

        f32x4 s[4];
        #pragma unroll
        for (int n = 0; n < 4; ++n) s[n] = zero;
        #pragma unroll
        for (int n = 0; n < 4; ++n){
            bf16x8 kf0 = ldfrag(Kl, n*16 + li, g*16);
            bf16x8 kf1 = ldfrag(Kl, n*16 + li, g*16 + 64);
            s[n] = MFMA16(qf0, kf0, s[n]);
            s[n] = MFMA16(qf1, kf1, s[n]);
        }

        float p[4][4];
        #pragma unroll
        for (int r = 0; r < 4; ++r){
            float rm = fmaxf(fmaxf(s[0][r], s[1][r]), fmaxf(s[2][r], s[3][r]));
            rm = fmaxf(rm, __shfl_xor(rm, 1));
            rm = fmaxf(rm, __shfl_xor(rm, 2));
            rm = fmaxf(rm, __shfl_xor(rm, 4));
            rm = fmaxf(rm, __shfl_xor(rm, 8));
            const float mn  = fmaxf(mrow[r], rm);
            const float fsc = __expf(mrow[r] - mn);
            mrow[r] = mn;
            float rs = 0.f;
            #pragma unroll
            for (int n = 0; n < 4; ++n){ p[n][r] = __expf(s[n][r] - mn); rs += p[n][r]; }
            rs += __shfl_xor(rs, 1);
            rs += __shfl_xor(rs, 2);
            rs += __shfl_xor(rs, 4);
            rs += __shfl_xor(rs, 8);
            lrow[r] = lrow[r]*fsc + rs;
            #pragma unroll
            for (int dt = 0; dt < 4; ++dt) acc_o[dt][r] *= fsc;
        }

        u16* pw = &Pl[w][0];
        #pragma unroll
        for (int n = 0; n < 4; ++n){
            #pragma unroll
            for (int r = 0; r < 4; ++r)
                *(u16*)((char*)pw + swz(g*4 + r, n*32 + li*2)) = f2bf(p[n][r]);
        }
        __syncthreads();

        #pragma unroll
        for (int ks = 0; ks < 2; ++ks){
            bf16x8 pf = ldfrag(pw, li, g*16 + ks*64);
            #pragma unroll
            for (int dt = 0; dt < 4; ++dt){
                bf16x8 vf = ldfrag(Vl, dt*16 + li, g*16 + ks*64);
                acc_o[dt] = MFMA16(pf, vf, acc_o[dt]);
            }
        }
    }

    #pragma unroll
    for (int r = 0; r < 4; ++r){
        const float il = 1.0f / lrow[r];
        const int   i  = ib*64 + w*16 + g*4 + r;
        const size_t ob = (((size_t)b*S_LEN + i)*NH + h)*64;
        #pragma unroll
        for (int dt = 0; dt < 4; ++dt)
            out[ob + dt*16 + li] = acc_o[dt][r] * il;
        if (li == 0){
            m_s [bh*S_LEN + i] = mrow[r];
            il_s[bh*S_LEN + i] = il;
        }
    }
}

__global__ __launch_bounds__(256, 2)
void k2_tv(const float* __restrict__ q, const float* __restrict__ k,
           const float* __restrict__ vkq, const float* __restrict__ ssc,
           float* __restrict__ out2, const float* __restrict__ m_s,
           const float* __restrict__ il_s){
    const int blk = blockIdx.x;
    const int bh  = blk >> 5;
    const int jb  = blk & 31;
    const int b   = bh >> 4;
    const int h   = bh & 15;
    const int lane = threadIdx.x & 63;
    const int w    = threadIdx.x >> 6;
    const int g    = lane >> 4;
    const int li   = lane & 15;

    const size_t base  = ((size_t)b*S_LEN)*1024 + (size_t)h*64;
    const float  scale = __expf(fminf(fmaxf(ssc[h], CLO), CHI));

    __shared__ __align__(16) u16 Ql[4096];
    __shared__ __align__(16) u16 Kl[4096];
    __shared__ __align__(16) u16 Vl[4096];
    __shared__ __align__(16) u16 Pl[4][1024];

    stage_rows(k + base + (size_t)jb*64*1024, Kl, 1.0f);
    __syncthreads();
    const bf16x8 kf0 = ldfrag(Kl, w*16 + li, g*16);
    const bf16x8 kf1 = ldfrag(Kl, w*16 + li, g*16 + 64);

    const f32x4 zero = {0.f, 0.f, 0.f, 0.f};
    f32x4 acc[4];
    #pragma unroll
    for (int i = 0; i < 4; ++i) acc[i] = zero;

    for (int it = 0; it < NT; ++it){
        __syncthreads();
        stage_rows(q + base + (size_t)it*64*1024, Ql, scale);
        stage_T  (vkq + base + (size_t)it*64*1024, Vl);
        __syncthreads();

        f32x4 s[4];
        #pragma unroll
        for (int n = 0; n < 4; ++n) s[n] = zero;
        #pragma unroll
        for (int n = 0; n < 4; ++n){
            bf16x8 qb0 = ldfrag(Ql, n*16 + li, g*16);
            bf16x8 qb1 = ldfrag(Ql, n*16 + li, g*16 + 64);
            s[n] = MFMA16(kf0, qb0, s[n]);
            s[n] = MFMA16(kf1, qb1, s[n]);
        }

        u16* pw = &Pl[w][0];
        #pragma unroll
        for (int n = 0; n < 4; ++n){
            const int   ig = it*64 + n*16 + li;
            const float mi = m_s [bh*S_LEN + ig];
            const float ii = il_s[bh*S_LEN + ig];
            #pragma unroll
            for (int r = 0; r < 4; ++r){
                const float pv = __expf(s[n][r] - mi) * ii;
                *(u16*)((char*)pw + swz(g*4 + r, n*32 + li*2)) = f2bf(pv);
            }
        }
        __syncthreads();

        #pragma unroll
        for (int ks = 0; ks < 2; ++ks){
            bf16x8 pf = ldfrag(pw, li, g*16 + ks*64);
            #pragma unroll
            for (int dt = 0; dt < 4; ++dt){
                bf16x8 vf = ldfrag(Vl, dt*16 + li, g*16 + ks*64);
                acc[dt] = MFMA16(pf, vf, acc[dt]);
            }
        }
    }

    #pragma unroll
    for (int r = 0; r < 4; ++r){
        const int j = jb*64 + w*16 + g*4 + r;
        const size_t ob = (((size_t)b*S_LEN + j)*NH + h)*64;
        #pragma unroll
        for (int dt = 0; dt < 4; ++dt)
            out2[ob + dt*16 + li] = acc[dt][r];
    }
}

// ---------------------------------------------------------------------------

extern "C" void kernel_launch(void* const* d_in, const int* in_sizes, int n_in,
                              void* d_out, int out_size, void* d_ws, size_t ws_size,
                              hipStream_t stream){
    const float* q   = (const float*)d_in[0];
    const float* k   = (const float*)d_in[1];
    const float* v   = (const float*)d_in[2];
    const float* vkq = (const float*)d_in[3];
    const float* ssc = (const float*)d_in[4];
    float* out  = (float*)d_out;
    float* out2 = out + (size_t)NB*S_LEN*NH*64;

    const size_t ELEMS = (size_t)NB*S_LEN*NH*64;           // 8,388,608 per tensor
    const size_t NEED  = 4*ELEMS*sizeof(u16)               // 64 MB bf16 tensors
                       + (size_t)NB*NH*S_LEN*sizeof(float);// 0.5 MB il stats

    if (ws_size >= NEED){
        u16* qn  = (u16*)d_ws;
        u16* kn  = qn  + ELEMS;
        u16* vt  = kn  + ELEMS;
        u16* vkt = vt  + ELEMS;
        float* il_s = (float*)(vkt + ELEMS);

        prep_kern<<<dim3(NB*NH*NT, 4), 256, 0, stream>>>(q, k, v, vkq, ssc,
                                                         qn, kn, vt, vkt);
        k1f<<<NB*NH*16, 256, 0, stream>>>(qn, kn, vt, ssc, out, il_s);
        k2f<<<NB*NH*16, 256, 0, stream>>>(qn, kn, vkt, ssc, out2, il_s);
    } else {
        float* m_s  = (float*)d_ws;
        float* il_s = m_s + (size_t)NB*NH*S_LEN;
        k1_flash<<<NB*NH*NT, 256, 0, stream>>>(q, k, v, ssc, out, m_s, il_s);
        k2_tv  <<<NB*NH*NT, 256, 0, stream>>>(q, k, vkq, ssc, out2, m_s, il_s);
    }
}